// Round 14
// baseline (252.251 us; speedup 1.0000x reference)
//
#include <hip/hip_runtime.h>

typedef _Float16 f16x8 __attribute__((ext_vector_type(8)));
typedef float f32x4 __attribute__((ext_vector_type(4)));

#define GLD16(gp, lp) __builtin_amdgcn_global_load_lds(                     \
    (const __attribute__((address_space(1))) void*)(gp),                    \
    (__attribute__((address_space(3))) void*)(lp), 16, 0, 0)

// XCD-aware swizzle of the flattened 2D grid (requires nwg % 8 == 0).
__device__ inline void xcd_swizzle(int& bx, int& by) {
    const int nwg = gridDim.x * gridDim.y;
    const int flat = blockIdx.y * gridDim.x + blockIdx.x;
    const int cpx = nwg >> 3;
    const int swz = (flat & 7) * cpx + (flat >> 3);
    bx = swz % gridDim.x;
    by = swz / gridDim.x;
}

// ---------------------------------------------------------------------------
// Pipelined plain NT GEMM, 128x128 tile, BK=32, 4 waves (2M x 2N: 64x64/wave),
// TRIPLE-buffered LDS (48 KB -> 3 blocks/CU), single barrier per K-tile,
// K-loop unrolled x3, counted vmcnt(4). Multi-block co-residency lets one
// block's DS burst overlap another block's MFMA window (m114 mechanism).
// MODE 0: fp32 out (+bias).  MODE 1: fp16 out (+bias).
// MODE 2: fp16 out, per-batch transposed (v): out[(b*1024+col)*2048+s].
// MODE 3: fp16 out (+bias) + residual Ca for col < CaCols (qk projection).
// Per-element K-accumulation order identical to prior rounds (bit-exact).
// ---------------------------------------------------------------------------
template <int MODE>
__global__ __launch_bounds__(256, 3)
void gemm_pl128(const _Float16* __restrict__ A, const _Float16* __restrict__ B,
                void* __restrict__ Cm, _Float16* __restrict__ Ca,
                const float* __restrict__ bias,
                int K, int lda, int ldb, int ldc, int CaCols,
                size_t sA, size_t sB, size_t sC)
{
    __shared__ __align__(16) _Float16 lds[3][2][128 * 32];   // 48 KB
    const int tid = threadIdx.x, wave = tid >> 6, lane = tid & 63;
    const int z = blockIdx.z;
    int bx, by; xcd_swizzle(bx, by);
    const int m0 = by * 128, n0 = bx * 128;

    const int trow = tid >> 2;
    const int schunk = (tid & 3) ^ ((trow >> 1) & 3);
    const char* pA = (const char*)(A + (size_t)z * sA + (size_t)(m0 + trow) * lda) + schunk * 16;
    const char* pB = (const char*)(B + (size_t)z * sB + (size_t)(n0 + trow) * ldb) + schunk * 16;
    const size_t hA = (size_t)64 * lda * 2;
    const size_t hB = (size_t)64 * ldb * 2;

    auto stage = [&](int bf) {
        char* d0 = (char*)&lds[bf][0][0] + tid * 16;
        char* d1 = (char*)&lds[bf][1][0] + tid * 16;
        GLD16(pA, d0); GLD16(pA + hA, d0 + 4096);
        GLD16(pB, d1); GLD16(pB + hB, d1 + 4096);
        pA += 64; pB += 64;
    };

    const int wr = (wave >> 1) * 64, wcol = (wave & 1) * 64;
    const int fr = lane & 15;
    const int ckq = ((lane >> 4) ^ ((fr >> 1) & 3)) * 8;
    const int nt = K >> 5;
    const int aoff = (wr + fr) * 32 + ckq;
    const int boff = (wcol + fr) * 32 + ckq;

    const f32x4 zero = {0.f, 0.f, 0.f, 0.f};
    f32x4 acc[4][4];
#pragma unroll
    for (int i = 0; i < 4; ++i)
#pragma unroll
        for (int j = 0; j < 4; ++j) acc[i][j] = zero;

    stage(0); stage(1);
    asm volatile("s_waitcnt vmcnt(4)" ::: "memory");
    __builtin_amdgcn_s_barrier();
    __builtin_amdgcn_sched_barrier(0);

    for (int tb = 0; tb < nt; tb += 3) {
#pragma unroll
        for (int u = 0; u < 3; ++u) {
            const int t = tb + u;
            if (t < nt) {
                if (t + 2 < nt) stage((u + 2) % 3);   // compile-time buffer
                const _Float16* bA = &lds[u][0][0];
                const _Float16* bB = &lds[u][1][0];
                f16x8 af[4], bf4[4];
#pragma unroll
                for (int i = 0; i < 4; ++i)
                    af[i] = *(const f16x8*)(bA + aoff + i * 512);
#pragma unroll
                for (int j = 0; j < 4; ++j)
                    bf4[j] = *(const f16x8*)(bB + boff + j * 512);
                __builtin_amdgcn_s_setprio(1);
#pragma unroll
                for (int i = 0; i < 4; ++i)
#pragma unroll
                    for (int j = 0; j < 4; ++j)
                        acc[i][j] = __builtin_amdgcn_mfma_f32_16x16x32_f16(af[i], bf4[j], acc[i][j], 0, 0, 0);
                __builtin_amdgcn_s_setprio(0);
                __builtin_amdgcn_sched_barrier(0);
                if (t + 2 < nt) { asm volatile("s_waitcnt vmcnt(4)" ::: "memory"); }
                else           { asm volatile("s_waitcnt vmcnt(0)" ::: "memory"); }
                __builtin_amdgcn_s_barrier();
                __builtin_amdgcn_sched_barrier(0);
            }
        }
    }

    const int r0 = (lane >> 4) * 4;
#pragma unroll
    for (int j = 0; j < 4; ++j) {
        const int col = n0 + wcol + j * 16 + fr;
        const float bv = bias ? bias[col] : 0.0f;
#pragma unroll
        for (int i = 0; i < 4; ++i) {
            const int row = m0 + wr + i * 16 + r0;
            if constexpr (MODE == 0) {
                float* p = (float*)Cm + (size_t)z * sC + (size_t)row * ldc + col;
                p[0]               = acc[i][j][0] + bv;
                p[(size_t)ldc]     = acc[i][j][1] + bv;
                p[(size_t)2 * ldc] = acc[i][j][2] + bv;
                p[(size_t)3 * ldc] = acc[i][j][3] + bv;
            } else if constexpr (MODE == 1) {
                _Float16* p = (_Float16*)Cm + (size_t)z * sC + (size_t)row * ldc + col;
                p[0]               = (_Float16)(acc[i][j][0] + bv);
                p[(size_t)ldc]     = (_Float16)(acc[i][j][1] + bv);
                p[(size_t)2 * ldc] = (_Float16)(acc[i][j][2] + bv);
                p[(size_t)3 * ldc] = (_Float16)(acc[i][j][3] + bv);
            } else if constexpr (MODE == 2) {
                const int bb = row >> 11, s = row & 2047;
                _Float16* p = (_Float16*)Cm + (((size_t)(bb << 10) + col) << 11) + s;
                p[0] = (_Float16)(acc[i][j][0] + bv);
                p[1] = (_Float16)(acc[i][j][1] + bv);
                p[2] = (_Float16)(acc[i][j][2] + bv);
                p[3] = (_Float16)(acc[i][j][3] + bv);
            } else {   // MODE 3: fp16 hi + residual for col < CaCols
#pragma unroll
                for (int r = 0; r < 4; ++r) {
                    const float val = acc[i][j][r] + bv;
                    const size_t idx = (size_t)z * sC + (size_t)(row + r) * ldc + col;
                    const _Float16 hv = (_Float16)val;
                    ((_Float16*)Cm)[idx] = hv;
                    if (col < CaCols) Ca[idx] = (_Float16)(val - (float)hv);
                }
            }
        }
    }
}

// ---------------------------------------------------------------------------
// Split-A NT GEMM, 128x128 tile, BK=32, 4 waves (2M x 2N: 64x64/wave),
// TRIPLE-buffered LDS (72 KB -> 2 blocks/CU), single barrier per K-tile,
// K-loop unrolled x3, counted vmcnt(6).
//   C = Ah*B + Al*B  (A residual unscaled), fp32 out.  Bit-exact chains.
// ---------------------------------------------------------------------------
__global__ __launch_bounds__(256, 2)
void gemm_spa128(const _Float16* __restrict__ Ah, const _Float16* __restrict__ Al,
                 const _Float16* __restrict__ B, float* __restrict__ Cm,
                 int K, int lda, int ldb, int ldc,
                 size_t sA, size_t sB, size_t sC)
{
    __shared__ __align__(16) _Float16 lds[3][3][128 * 32];   // 72 KB
    const int tid = threadIdx.x, wave = tid >> 6, lane = tid & 63;
    const int z = blockIdx.z;
    int bx, by; xcd_swizzle(bx, by);
    const int m0 = by * 128, n0 = bx * 128;

    const int trow = tid >> 2;
    const int schunk = (tid & 3) ^ ((trow >> 1) & 3);
    const char* pAh = (const char*)(Ah + (size_t)z * sA + (size_t)(m0 + trow) * lda) + schunk * 16;
    const char* pAl = (const char*)(Al + (size_t)z * sA + (size_t)(m0 + trow) * lda) + schunk * 16;
    const char* pB  = (const char*)(B  + (size_t)z * sB + (size_t)(n0 + trow) * ldb) + schunk * 16;
    const size_t hA = (size_t)64 * lda * 2;
    const size_t hB = (size_t)64 * ldb * 2;

    auto stage = [&](int bf) {
        char* d0 = (char*)&lds[bf][0][0] + tid * 16;
        char* d1 = (char*)&lds[bf][1][0] + tid * 16;
        char* d2 = (char*)&lds[bf][2][0] + tid * 16;
        GLD16(pAh, d0); GLD16(pAh + hA, d0 + 4096);
        GLD16(pAl, d1); GLD16(pAl + hA, d1 + 4096);
        GLD16(pB,  d2); GLD16(pB  + hB, d2 + 4096);
        pAh += 64; pAl += 64; pB += 64;
    };

    const int wr = (wave >> 1) * 64, wcol = (wave & 1) * 64;
    const int fr = lane & 15;
    const int ckq = ((lane >> 4) ^ ((fr >> 1) & 3)) * 8;
    const int nt = K >> 5;
    const int aoff = (wr + fr) * 32 + ckq;
    const int boff = (wcol + fr) * 32 + ckq;

    const f32x4 zero = {0.f, 0.f, 0.f, 0.f};
    f32x4 acc[4][4];
#pragma unroll
    for (int i = 0; i < 4; ++i)
#pragma unroll
        for (int j = 0; j < 4; ++j) acc[i][j] = zero;

    stage(0); stage(1);
    asm volatile("s_waitcnt vmcnt(6)" ::: "memory");
    __builtin_amdgcn_s_barrier();
    __builtin_amdgcn_sched_barrier(0);

    for (int tb = 0; tb < nt; tb += 3) {
#pragma unroll
        for (int u = 0; u < 3; ++u) {
            const int t = tb + u;
            if (t < nt) {
                if (t + 2 < nt) stage((u + 2) % 3);
                const _Float16* bAh = &lds[u][0][0];
                const _Float16* bAl = &lds[u][1][0];
                const _Float16* bB  = &lds[u][2][0];
                f16x8 af[4], al4[4], bf4[4];
#pragma unroll
                for (int i = 0; i < 4; ++i) {
                    af[i]  = *(const f16x8*)(bAh + aoff + i * 512);
                    al4[i] = *(const f16x8*)(bAl + aoff + i * 512);
                }
#pragma unroll
                for (int j = 0; j < 4; ++j)
                    bf4[j] = *(const f16x8*)(bB + boff + j * 512);
                __builtin_amdgcn_s_setprio(1);
#pragma unroll
                for (int i = 0; i < 4; ++i)
#pragma unroll
                    for (int j = 0; j < 4; ++j) {
                        acc[i][j] = __builtin_amdgcn_mfma_f32_16x16x32_f16(af[i],  bf4[j], acc[i][j], 0, 0, 0);
                        acc[i][j] = __builtin_amdgcn_mfma_f32_16x16x32_f16(al4[i], bf4[j], acc[i][j], 0, 0, 0);
                    }
                __builtin_amdgcn_s_setprio(0);
                __builtin_amdgcn_sched_barrier(0);
                if (t + 2 < nt) { asm volatile("s_waitcnt vmcnt(6)" ::: "memory"); }
                else           { asm volatile("s_waitcnt vmcnt(0)" ::: "memory"); }
                __builtin_amdgcn_s_barrier();
                __builtin_amdgcn_sched_barrier(0);
            }
        }
    }

    const int r0 = (lane >> 4) * 4;
#pragma unroll
    for (int j = 0; j < 4; ++j) {
        const int col = n0 + wcol + j * 16 + fr;
#pragma unroll
        for (int i = 0; i < 4; ++i) {
            const int row = m0 + wr + i * 16 + r0;
            float* p = Cm + (size_t)z * sC + (size_t)row * ldc + col;
            p[0]               = acc[i][j][0];
            p[(size_t)ldc]     = acc[i][j][1];
            p[(size_t)2 * ldc] = acc[i][j][2];
            p[(size_t)3 * ldc] = acc[i][j][3];
        }
    }
}

// ---------------------------------------------------------------------------
// fp32 -> fp16 (hi only; residual path unused since round 7).
// ---------------------------------------------------------------------------
__global__ __launch_bounds__(256)
void cvt_split_f16(const float* __restrict__ in, _Float16* __restrict__ hi,
                   _Float16* __restrict__ lo, int n8)
{
    const int t = blockIdx.x * 256 + threadIdx.x;
    if (t >= n8) return;
    const float4* p = (const float4*)in + (size_t)t * 2;
    const float4 a = p[0], b = p[1];
    const float v[8] = {a.x, a.y, a.z, a.w, b.x, b.y, b.z, b.w};
    f16x8 h, l;
#pragma unroll
    for (int j = 0; j < 8; ++j) {
        const _Float16 hv = (_Float16)v[j];
        h[j] = hv;
        l[j] = (_Float16)(v[j] - (float)hv);
    }
    ((f16x8*)hi)[t] = h;
    if (lo) ((f16x8*)lo)[t] = l;
}

// ---------------------------------------------------------------------------
// Batched 1024x1024 fp32 -> fp16 transpose of the 4 weight matrices (z=0..3).
// ---------------------------------------------------------------------------
__global__ __launch_bounds__(256)
void transpose4_f16(const float* __restrict__ W0, const float* __restrict__ W1,
                    const float* __restrict__ W2, const float* __restrict__ W3,
                    _Float16* __restrict__ T0, _Float16* __restrict__ T1,
                    _Float16* __restrict__ T2, _Float16* __restrict__ T3)
{
    constexpr int N = 1024;
    const int zi = blockIdx.z;
    const float* W = (zi == 0) ? W0 : (zi == 1) ? W1 : (zi == 2) ? W2 : W3;
    _Float16*   T = (zi == 0) ? T0 : (zi == 1) ? T1 : (zi == 2) ? T2 : T3;
    __shared__ float t[32][33];
    const int c0 = blockIdx.x * 32, r0 = blockIdx.y * 32;
    const int tx = threadIdx.x & 31, ty = threadIdx.x >> 5;
#pragma unroll
    for (int r = ty; r < 32; r += 8)
        t[r][tx] = W[(size_t)(r0 + r) * N + (c0 + tx)];
    __syncthreads();
#pragma unroll
    for (int r = ty; r < 32; r += 8)
        T[(size_t)(c0 + r) * N + (r0 + tx)] = (_Float16)t[tx][r];
}

// ---------------------------------------------------------------------------
// Concatenate two 1024-float bias vectors.
// ---------------------------------------------------------------------------
__global__ __launch_bounds__(256)
void concat_bias(const float* __restrict__ a, const float* __restrict__ b,
                 float* __restrict__ o)
{
    const int t = blockIdx.x * 256 + threadIdx.x;
    o[t] = (t < 1024) ? a[t] : b[t - 1024];
}

// ---------------------------------------------------------------------------
// Row softmax: fp32 scores [rows, 2048] -> fp16 probs. One block per row.
// ---------------------------------------------------------------------------
__global__ __launch_bounds__(256)
void softmax_rows(const float* __restrict__ S, _Float16* __restrict__ P)
{
    const int row = blockIdx.x;
    const float* s = S + (size_t)row * 2048 + threadIdx.x * 8;
    float v[8];
    const float4 a = *(const float4*)s;
    const float4 b = *(const float4*)(s + 4);
    v[0] = a.x; v[1] = a.y; v[2] = a.z; v[3] = a.w;
    v[4] = b.x; v[5] = b.y; v[6] = b.z; v[7] = b.w;
    float mx = v[0];
#pragma unroll
    for (int j = 1; j < 8; ++j) mx = fmaxf(mx, v[j]);
    for (int off = 32; off; off >>= 1) mx = fmaxf(mx, __shfl_xor(mx, off, 64));
    __shared__ float redm[4], reds[4];
    const int wv = threadIdx.x >> 6;
    if ((threadIdx.x & 63) == 0) redm[wv] = mx;
    __syncthreads();
    mx = fmaxf(fmaxf(redm[0], redm[1]), fmaxf(redm[2], redm[3]));
    float sum = 0.f;
#pragma unroll
    for (int j = 0; j < 8; ++j) { v[j] = expf(v[j] - mx); sum += v[j]; }
    for (int off = 32; off; off >>= 1) sum += __shfl_xor(sum, off, 64);
    if ((threadIdx.x & 63) == 0) reds[wv] = sum;
    __syncthreads();
    const float inv = 1.0f / (reds[0] + reds[1] + reds[2] + reds[3]);
    f16x8 o;
#pragma unroll
    for (int j = 0; j < 8; ++j) o[j] = (_Float16)(v[j] * inv);
    *(f16x8*)(P + (size_t)row * 2048 + threadIdx.x * 8) = o;
}

// ---------------------------------------------------------------------------
extern "C" void kernel_launch(void* const* d_in, const int* in_sizes, int n_in,
                              void* d_out, int out_size, void* d_ws, size_t ws_size,
                              hipStream_t stream)
{
    (void)in_sizes; (void)n_in; (void)out_size;
    const float* x  = (const float*)d_in[0];
    const float* Wq = (const float*)d_in[1];
    const float* bq = (const float*)d_in[2];
    const float* Wk = (const float*)d_in[3];
    const float* bk = (const float*)d_in[4];
    const float* Wv = (const float*)d_in[5];
    const float* bv = (const float*)d_in[6];
    const float* Wo = (const float*)d_in[7];
    const float* bo = (const float*)d_in[8];
    float* out = (float*)d_out;

    constexpr int S = 2048, D = 1024, H = 1024, NBATCH = 4;
    constexpr size_t M  = (size_t)NBATCH * S;   // 8192
    constexpr size_t SH = (size_t)S * H;        // per-batch q/k/v elems
    constexpr size_t SS = (size_t)S * S;        // per-batch score elems
    constexpr size_t QK = (size_t)S * 2048;     // per-batch fused qk row-block

    char* w = (char*)d_ws;
    size_t off = 0;
    auto alloc = [&](size_t bytes) -> char* {
        char* p = w + off;
        off += (bytes + 255) & ~(size_t)255;
        return p;
    };

    _Float16* xh   = (_Float16*)alloc(M * D * 2);
    _Float16* wqkT = (_Float16*)alloc((size_t)2 * D * H * 2);  // [2048][1024]
    _Float16* wvh  = (_Float16*)alloc((size_t)D * H * 2);
    _Float16* woh  = (_Float16*)alloc((size_t)H * D * 2);
    float*    bqk  = (float*)alloc(2048 * 4);
    _Float16* qkh  = (_Float16*)alloc(M * 2048 * 2);  // [8192][2048] q|k hi
    _Float16* qkl  = (_Float16*)alloc(M * 2048 * 2);  // residual (q cols only)
    _Float16* vT   = (_Float16*)alloc(M * H * 2);
    _Float16* yh   = xh;  // x dead after projections; reuse for y

    int NB = 1;
    if (ws_size >= off + (size_t)4 * SS * 4 + (size_t)4 * SS * 2 + 1024) NB = 4;
    float*    sc = (float*)alloc((size_t)NB * SS * 4);
    _Float16* Ph = (_Float16*)alloc((size_t)NB * SS * 2);

    // ---- convert / transpose / concat ----
    cvt_split_f16<<<dim3((unsigned)(M * D / 8 / 256)), 256, 0, stream>>>(
        x, xh, nullptr, (int)(M * D / 8));
    transpose4_f16<<<dim3(32, 32, 4), 256, 0, stream>>>(
        Wq, Wk, Wv, Wo, wqkT, wqkT + (size_t)D * H, wvh, woh);
    concat_bias<<<dim3(8), 256, 0, stream>>>(bq, bk, bqk);

    // ---- fused q|k projection: 128^2 tiles, grid 16x64 = 1024 wg ----
    gemm_pl128<3><<<dim3(2048 / 128, M / 128), 256, 0, stream>>>(
        xh, wqkT, qkh, qkl, bqk,
        D, D, D, 2048, /*CaCols=*/1024, 0, 0, 0);

    // ---- v projection (transposed out): grid 8x64 = 512 wg ----
    gemm_pl128<2><<<dim3(H / 128, M / 128), 256, 0, stream>>>(
        xh, wvh, vT, nullptr, bv, D, D, D, 0, 0, 0, 0, 0);

    // ---- attention ----
    for (int b0 = 0; b0 < NBATCH; b0 += NB) {
        // scores = (qh+ql) * kh^T (split-A 128^2): grid 16x16x4 = 1024 wg
        gemm_spa128<<<dim3(S / 128, S / 128, NB), 256, 0, stream>>>(
            qkh + (size_t)b0 * QK, qkl + (size_t)b0 * QK,
            qkh + (size_t)b0 * QK + 1024,
            sc, H, 2048, 2048, S, QK, QK, SS);
        softmax_rows<<<dim3(NB * S), 256, 0, stream>>>(sc, Ph);
        // PV: grid 8x16x4 = 512 wg
        gemm_pl128<1><<<dim3(H / 128, S / 128, NB), 256, 0, stream>>>(
            Ph, vT + (size_t)b0 * SH, yh + (size_t)b0 * SH, nullptr, nullptr,
            S, S, S, H, 0, SS, SH, SH);
    }

    // ---- output projection: grid 8x64 = 512 wg ----
    gemm_pl128<0><<<dim3(D / 128, M / 128), 256, 0, stream>>>(
        yh, woh, out, nullptr, bo, H, H, H, D, 0, 0, 0, 0);
}

// Round 15
// 237.507 us; speedup vs baseline: 1.0621x; 1.0621x over previous
//
#include <hip/hip_runtime.h>

typedef _Float16 f16x8 __attribute__((ext_vector_type(8)));
typedef float f32x4 __attribute__((ext_vector_type(4)));

#define GLD16(gp, lp) __builtin_amdgcn_global_load_lds(                     \
    (const __attribute__((address_space(1))) void*)(gp),                    \
    (__attribute__((address_space(3))) void*)(lp), 16, 0, 0)

// XCD-aware swizzle of the flattened 2D grid (requires nwg % 8 == 0).
__device__ inline void xcd_swizzle(int& bx, int& by) {
    const int nwg = gridDim.x * gridDim.y;
    const int flat = blockIdx.y * gridDim.x + blockIdx.x;
    const int cpx = nwg >> 3;
    const int swz = (flat & 7) * cpx + (flat >> 3);
    bx = swz % gridDim.x;
    by = swz / gridDim.x;
}

// ---------------------------------------------------------------------------
// Pipelined plain NT GEMM, 128x256 tile, BK=32, 8 waves (2M x 4N: 64x64/wave),
// TRIPLE-buffered LDS (72 KB), single barrier per K-tile; K-loop unrolled x3
// so buffer indices / LDS bases are compile-time.
// MODE 0: fp32 out (+bias).  MODE 1: fp16 out (+bias).
// MODE 2: fp16 out, per-batch transposed (v): out[(b*1024+col)*2048+s].
// K-chain order identical to previous rounds (bit-exact outputs).
// ---------------------------------------------------------------------------
template <int MODE>
__global__ __launch_bounds__(512, 2)
void gemm_pl(const _Float16* __restrict__ A, const _Float16* __restrict__ B,
             void* __restrict__ C, const float* __restrict__ bias,
             int K, int lda, int ldb, int ldc, size_t sA, size_t sB, size_t sC)
{
    __shared__ __align__(16) _Float16 lds[3][(128 + 256) * 32];   // 72 KB
    const int tid = threadIdx.x, wave = tid >> 6, lane = tid & 63;
    const int z = blockIdx.z;
    int bx, by; xcd_swizzle(bx, by);
    const int m0 = by * 128, n0 = bx * 256;

    const int trow = tid >> 2;
    const int schunk = (tid & 3) ^ ((trow >> 1) & 3);
    const char* pA = (const char*)(A + (size_t)z * sA + (size_t)(m0 + trow) * lda) + schunk * 16;
    const char* pB = (const char*)(B + (size_t)z * sB + (size_t)(n0 + trow) * ldb) + schunk * 16;
    const size_t hB = (size_t)128 * ldb * 2;

    auto stage = [&](int bf) {
        char* dA = (char*)&lds[bf][0] + tid * 16;
        char* dB = (char*)&lds[bf][128 * 32] + tid * 16;
        GLD16(pA, dA);
        GLD16(pB, dB); GLD16(pB + hB, dB + 8192);
        pA += 64; pB += 64;
    };

    const int wr = (wave >> 2) * 64, wcol = (wave & 3) * 64;
    const int fr = lane & 15;
    const int ckq = ((lane >> 4) ^ ((fr >> 1) & 3)) * 8;
    const int nt = K >> 5;
    const int aoff = (wr + fr) * 32 + ckq;
    const int boff = (wcol + fr) * 32 + ckq;

    const f32x4 zero = {0.f, 0.f, 0.f, 0.f};
    f32x4 acc[4][4];
#pragma unroll
    for (int i = 0; i < 4; ++i)
#pragma unroll
        for (int j = 0; j < 4; ++j) acc[i][j] = zero;

    stage(0); stage(1);
    asm volatile("s_waitcnt vmcnt(3)" ::: "memory");
    __builtin_amdgcn_s_barrier();
    __builtin_amdgcn_sched_barrier(0);

    for (int tb = 0; tb < nt; tb += 3) {
#pragma unroll
        for (int u = 0; u < 3; ++u) {
            const int t = tb + u;
            if (t < nt) {
                if (t + 2 < nt) stage((u + 2) % 3);   // compile-time buffer
                const _Float16* bA = &lds[u][0];
                const _Float16* bB = &lds[u][128 * 32];
                f16x8 af[4], bf4[4];
#pragma unroll
                for (int i = 0; i < 4; ++i)
                    af[i] = *(const f16x8*)(bA + aoff + i * 512);
#pragma unroll
                for (int j = 0; j < 4; ++j)
                    bf4[j] = *(const f16x8*)(bB + boff + j * 512);
                __builtin_amdgcn_s_setprio(1);
#pragma unroll
                for (int i = 0; i < 4; ++i)
#pragma unroll
                    for (int j = 0; j < 4; ++j)
                        acc[i][j] = __builtin_amdgcn_mfma_f32_16x16x32_f16(af[i], bf4[j], acc[i][j], 0, 0, 0);
                __builtin_amdgcn_s_setprio(0);
                __builtin_amdgcn_sched_barrier(0);
                if (t + 2 < nt) { asm volatile("s_waitcnt vmcnt(3)" ::: "memory"); }
                else           { asm volatile("s_waitcnt vmcnt(0)" ::: "memory"); }
                __builtin_amdgcn_s_barrier();
                __builtin_amdgcn_sched_barrier(0);
            }
        }
    }

    const int r0 = (lane >> 4) * 4;
#pragma unroll
    for (int j = 0; j < 4; ++j) {
        const int col = n0 + wcol + j * 16 + fr;
        const float bv = bias ? bias[col] : 0.0f;
#pragma unroll
        for (int i = 0; i < 4; ++i) {
            const int row = m0 + wr + i * 16 + r0;
            if constexpr (MODE == 0) {
                float* p = (float*)C + (size_t)z * sC + (size_t)row * ldc + col;
                p[0]               = acc[i][j][0] + bv;
                p[(size_t)ldc]     = acc[i][j][1] + bv;
                p[(size_t)2 * ldc] = acc[i][j][2] + bv;
                p[(size_t)3 * ldc] = acc[i][j][3] + bv;
            } else if constexpr (MODE == 1) {
                _Float16* p = (_Float16*)C + (size_t)z * sC + (size_t)row * ldc + col;
                p[0]               = (_Float16)(acc[i][j][0] + bv);
                p[(size_t)ldc]     = (_Float16)(acc[i][j][1] + bv);
                p[(size_t)2 * ldc] = (_Float16)(acc[i][j][2] + bv);
                p[(size_t)3 * ldc] = (_Float16)(acc[i][j][3] + bv);
            } else {
                const int bb = row >> 11, s = row & 2047;
                _Float16* p = (_Float16*)C + (((size_t)(bb << 10) + col) << 11) + s;
                p[0] = (_Float16)(acc[i][j][0] + bv);
                p[1] = (_Float16)(acc[i][j][1] + bv);
                p[2] = (_Float16)(acc[i][j][2] + bv);
                p[3] = (_Float16)(acc[i][j][3] + bv);
            }
        }
    }
}

// ---------------------------------------------------------------------------
// Split-A NT GEMM, 256x256 tile, BK=32, 8 waves (4M x 2N: 64x128/wave),
// TRIPLE-buffered LDS (144 KB), single barrier per K-tile; K-loop unrolled x3.
//   C = Ah*B + Al*B  (A residual unscaled), fp32 acc.  Bit-exact chains.
// MODE 0: fp32 out.  MODE 1: fp16 hi out (+bias) + residual Ca for col<CaCols.
// ---------------------------------------------------------------------------
template <int MODE>
__global__ __launch_bounds__(512, 2)
void gemm_spa256(const _Float16* __restrict__ Ah, const _Float16* __restrict__ Al,
                 const _Float16* __restrict__ B,
                 void* __restrict__ Cm, _Float16* __restrict__ Ca,
                 const float* __restrict__ bias,
                 int K, int lda, int ldb, int ldc, int CaCols,
                 size_t sA, size_t sB, size_t sC)
{
    __shared__ __align__(16) _Float16 lds[3][3][256 * 32];   // 144 KB
    const int tid = threadIdx.x, wave = tid >> 6, lane = tid & 63;
    const int z = blockIdx.z;
    int bx, by; xcd_swizzle(bx, by);
    const int m0 = by * 256, n0 = bx * 256;

    const int trow = tid >> 2;
    const int schunk = (tid & 3) ^ ((trow >> 1) & 3);
    const char* pAh = (const char*)(Ah + (size_t)z * sA + (size_t)(m0 + trow) * lda) + schunk * 16;
    const char* pAl = (const char*)(Al + (size_t)z * sA + (size_t)(m0 + trow) * lda) + schunk * 16;
    const char* pB  = (const char*)(B  + (size_t)z * sB + (size_t)(n0 + trow) * ldb) + schunk * 16;
    const size_t hA = (size_t)128 * lda * 2;
    const size_t hB = (size_t)128 * ldb * 2;

    auto stage = [&](int bf) {
        char* d0 = (char*)&lds[bf][0][0] + tid * 16;
        char* d1 = (char*)&lds[bf][1][0] + tid * 16;
        char* d2 = (char*)&lds[bf][2][0] + tid * 16;
        GLD16(pAh, d0); GLD16(pAh + hA, d0 + 8192);
        GLD16(pAl, d1); GLD16(pAl + hA, d1 + 8192);
        GLD16(pB,  d2); GLD16(pB  + hB, d2 + 8192);
        pAh += 64; pAl += 64; pB += 64;
    };

    const int wr = (wave >> 1) * 64, wcol = (wave & 1) * 128;
    const int fr = lane & 15;
    const int ckq = ((lane >> 4) ^ ((fr >> 1) & 3)) * 8;
    const int nt = K >> 5;
    const int aoff = (wr + fr) * 32 + ckq;
    const int boff = (wcol + fr) * 32 + ckq;

    const f32x4 zero = {0.f, 0.f, 0.f, 0.f};
    f32x4 acc[4][8];
#pragma unroll
    for (int i = 0; i < 4; ++i)
#pragma unroll
        for (int j = 0; j < 8; ++j) acc[i][j] = zero;

    stage(0); stage(1);
    asm volatile("s_waitcnt vmcnt(6)" ::: "memory");
    __builtin_amdgcn_s_barrier();
    __builtin_amdgcn_sched_barrier(0);

    for (int tb = 0; tb < nt; tb += 3) {
#pragma unroll
        for (int u = 0; u < 3; ++u) {
            const int t = tb + u;
            if (t < nt) {
                if (t + 2 < nt) stage((u + 2) % 3);   // compile-time buffer
                const _Float16* bAh = &lds[u][0][0];
                const _Float16* bAl = &lds[u][1][0];
                const _Float16* bB  = &lds[u][2][0];
                f16x8 af[4], al4[4], bf8[8];
#pragma unroll
                for (int i = 0; i < 4; ++i) {
                    af[i]  = *(const f16x8*)(bAh + aoff + i * 512);
                    al4[i] = *(const f16x8*)(bAl + aoff + i * 512);
                }
#pragma unroll
                for (int j = 0; j < 8; ++j)
                    bf8[j] = *(const f16x8*)(bB + boff + j * 512);
                __builtin_amdgcn_s_setprio(1);
#pragma unroll
                for (int i = 0; i < 4; ++i)
#pragma unroll
                    for (int j = 0; j < 8; ++j) {
                        acc[i][j] = __builtin_amdgcn_mfma_f32_16x16x32_f16(af[i],  bf8[j], acc[i][j], 0, 0, 0);
                        acc[i][j] = __builtin_amdgcn_mfma_f32_16x16x32_f16(al4[i], bf8[j], acc[i][j], 0, 0, 0);
                    }
                __builtin_amdgcn_s_setprio(0);
                __builtin_amdgcn_sched_barrier(0);
                if (t + 2 < nt) { asm volatile("s_waitcnt vmcnt(6)" ::: "memory"); }
                else           { asm volatile("s_waitcnt vmcnt(0)" ::: "memory"); }
                __builtin_amdgcn_s_barrier();
                __builtin_amdgcn_sched_barrier(0);
            }
        }
    }

    const int r0 = (lane >> 4) * 4;
#pragma unroll
    for (int j = 0; j < 8; ++j) {
        const int col = n0 + wcol + j * 16 + fr;
        const float bv = (MODE == 1 && bias) ? bias[col] : 0.0f;
#pragma unroll
        for (int i = 0; i < 4; ++i) {
            const int row = m0 + wr + i * 16 + r0;
#pragma unroll
            for (int r = 0; r < 4; ++r) {
                const float val = acc[i][j][r] + bv;
                const size_t idx = (size_t)z * sC + (size_t)(row + r) * ldc + col;
                if constexpr (MODE == 0) {
                    ((float*)Cm)[idx] = val;
                } else {
                    const _Float16 hv = (_Float16)val;
                    ((_Float16*)Cm)[idx] = hv;
                    if (col < CaCols) Ca[idx] = (_Float16)(val - (float)hv);
                }
            }
        }
    }
}

// ---------------------------------------------------------------------------
// Plain NT GEMM, 256x256 tile, BK=32, 8 waves (4M x 2N), TRIPLE-buffered
// (96 KB), single barrier per K-tile; K-loop unrolled x3. C = A*B^T, fp32 acc.
// MODE 1: fp16 hi out (+bias) + residual Ca for col<CaCols.  Bit-exact chains.
// ---------------------------------------------------------------------------
template <int MODE>
__global__ __launch_bounds__(512, 2)
void gemm_nt256(const _Float16* __restrict__ A, const _Float16* __restrict__ B,
                void* __restrict__ Cm, _Float16* __restrict__ Ca,
                const float* __restrict__ bias,
                int K, int lda, int ldb, int ldc, int CaCols,
                size_t sA, size_t sB, size_t sC)
{
    __shared__ __align__(16) _Float16 lds[3][2][256 * 32];   // 96 KB
    const int tid = threadIdx.x, wave = tid >> 6, lane = tid & 63;
    const int z = blockIdx.z;
    int bx, by; xcd_swizzle(bx, by);
    const int m0 = by * 256, n0 = bx * 256;

    const int trow = tid >> 2;
    const int schunk = (tid & 3) ^ ((trow >> 1) & 3);
    const char* pA = (const char*)(A + (size_t)z * sA + (size_t)(m0 + trow) * lda) + schunk * 16;
    const char* pB = (const char*)(B + (size_t)z * sB + (size_t)(n0 + trow) * ldb) + schunk * 16;
    const size_t hA = (size_t)128 * lda * 2;
    const size_t hB = (size_t)128 * ldb * 2;

    auto stage = [&](int bf) {
        char* d0 = (char*)&lds[bf][0][0] + tid * 16;
        char* d1 = (char*)&lds[bf][1][0] + tid * 16;
        GLD16(pA, d0); GLD16(pA + hA, d0 + 8192);
        GLD16(pB, d1); GLD16(pB + hB, d1 + 8192);
        pA += 64; pB += 64;
    };

    const int wr = (wave >> 1) * 64, wcol = (wave & 1) * 128;
    const int fr = lane & 15;
    const int ckq = ((lane >> 4) ^ ((fr >> 1) & 3)) * 8;
    const int nt = K >> 5;
    const int aoff = (wr + fr) * 32 + ckq;
    const int boff = (wcol + fr) * 32 + ckq;

    const f32x4 zero = {0.f, 0.f, 0.f, 0.f};
    f32x4 acc[4][8];
#pragma unroll
    for (int i = 0; i < 4; ++i)
#pragma unroll
        for (int j = 0; j < 8; ++j) acc[i][j] = zero;

    stage(0); stage(1);
    asm volatile("s_waitcnt vmcnt(4)" ::: "memory");
    __builtin_amdgcn_s_barrier();
    __builtin_amdgcn_sched_barrier(0);

    for (int tb = 0; tb < nt; tb += 3) {
#pragma unroll
        for (int u = 0; u < 3; ++u) {
            const int t = tb + u;
            if (t < nt) {
                if (t + 2 < nt) stage((u + 2) % 3);
                const _Float16* bA = &lds[u][0][0];
                const _Float16* bB = &lds[u][1][0];
                f16x8 af[4], bf8[8];
#pragma unroll
                for (int i = 0; i < 4; ++i)
                    af[i] = *(const f16x8*)(bA + aoff + i * 512);
#pragma unroll
                for (int j = 0; j < 8; ++j)
                    bf8[j] = *(const f16x8*)(bB + boff + j * 512);
                __builtin_amdgcn_s_setprio(1);
#pragma unroll
                for (int i = 0; i < 4; ++i)
#pragma unroll
                    for (int j = 0; j < 8; ++j)
                        acc[i][j] = __builtin_amdgcn_mfma_f32_16x16x32_f16(af[i], bf8[j], acc[i][j], 0, 0, 0);
                __builtin_amdgcn_s_setprio(0);
                __builtin_amdgcn_sched_barrier(0);
                if (t + 2 < nt) { asm volatile("s_waitcnt vmcnt(4)" ::: "memory"); }
                else           { asm volatile("s_waitcnt vmcnt(0)" ::: "memory"); }
                __builtin_amdgcn_s_barrier();
                __builtin_amdgcn_sched_barrier(0);
            }
        }
    }

    const int r0 = (lane >> 4) * 4;
#pragma unroll
    for (int j = 0; j < 8; ++j) {
        const int col = n0 + wcol + j * 16 + fr;
        const float bv = bias ? bias[col] : 0.0f;
#pragma unroll
        for (int i = 0; i < 4; ++i) {
            const int row = m0 + wr + i * 16 + r0;
#pragma unroll
            for (int r = 0; r < 4; ++r) {
                const float val = acc[i][j][r] + bv;
                const size_t idx = (size_t)z * sC + (size_t)(row + r) * ldc + col;
                const _Float16 hv = (_Float16)val;
                ((_Float16*)Cm)[idx] = hv;
                if (col < CaCols) Ca[idx] = (_Float16)(val - (float)hv);
            }
        }
    }
}

// ---------------------------------------------------------------------------
// fp32 -> fp16 (hi only; residual path unused since round 7).
// ---------------------------------------------------------------------------
__global__ __launch_bounds__(256)
void cvt_split_f16(const float* __restrict__ in, _Float16* __restrict__ hi,
                   _Float16* __restrict__ lo, int n8)
{
    const int t = blockIdx.x * 256 + threadIdx.x;
    if (t >= n8) return;
    const float4* p = (const float4*)in + (size_t)t * 2;
    const float4 a = p[0], b = p[1];
    const float v[8] = {a.x, a.y, a.z, a.w, b.x, b.y, b.z, b.w};
    f16x8 h, l;
#pragma unroll
    for (int j = 0; j < 8; ++j) {
        const _Float16 hv = (_Float16)v[j];
        h[j] = hv;
        l[j] = (_Float16)(v[j] - (float)hv);
    }
    ((f16x8*)hi)[t] = h;
    if (lo) ((f16x8*)lo)[t] = l;
}

// ---------------------------------------------------------------------------
// Batched 1024x1024 fp32 -> fp16 transpose of the 4 weight matrices (z=0..3).
// ---------------------------------------------------------------------------
__global__ __launch_bounds__(256)
void transpose4_f16(const float* __restrict__ W0, const float* __restrict__ W1,
                    const float* __restrict__ W2, const float* __restrict__ W3,
                    _Float16* __restrict__ T0, _Float16* __restrict__ T1,
                    _Float16* __restrict__ T2, _Float16* __restrict__ T3)
{
    constexpr int N = 1024;
    const int zi = blockIdx.z;
    const float* W = (zi == 0) ? W0 : (zi == 1) ? W1 : (zi == 2) ? W2 : W3;
    _Float16*   T = (zi == 0) ? T0 : (zi == 1) ? T1 : (zi == 2) ? T2 : T3;
    __shared__ float t[32][33];
    const int c0 = blockIdx.x * 32, r0 = blockIdx.y * 32;
    const int tx = threadIdx.x & 31, ty = threadIdx.x >> 5;
#pragma unroll
    for (int r = ty; r < 32; r += 8)
        t[r][tx] = W[(size_t)(r0 + r) * N + (c0 + tx)];
    __syncthreads();
#pragma unroll
    for (int r = ty; r < 32; r += 8)
        T[(size_t)(c0 + r) * N + (r0 + tx)] = (_Float16)t[tx][r];
}

// ---------------------------------------------------------------------------
// Concatenate two 1024-float bias vectors.
// ---------------------------------------------------------------------------
__global__ __launch_bounds__(256)
void concat_bias(const float* __restrict__ a, const float* __restrict__ b,
                 float* __restrict__ o)
{
    const int t = blockIdx.x * 256 + threadIdx.x;
    o[t] = (t < 1024) ? a[t] : b[t - 1024];
}

// ---------------------------------------------------------------------------
// Row softmax: fp32 scores [rows, 2048] -> fp16 probs. One block per row.
// ---------------------------------------------------------------------------
__global__ __launch_bounds__(256)
void softmax_rows(const float* __restrict__ S, _Float16* __restrict__ P)
{
    const int row = blockIdx.x;
    const float* s = S + (size_t)row * 2048 + threadIdx.x * 8;
    float v[8];
    const float4 a = *(const float4*)s;
    const float4 b = *(const float4*)(s + 4);
    v[0] = a.x; v[1] = a.y; v[2] = a.z; v[3] = a.w;
    v[4] = b.x; v[5] = b.y; v[6] = b.z; v[7] = b.w;
    float mx = v[0];
#pragma unroll
    for (int j = 1; j < 8; ++j) mx = fmaxf(mx, v[j]);
    for (int off = 32; off; off >>= 1) mx = fmaxf(mx, __shfl_xor(mx, off, 64));
    __shared__ float redm[4], reds[4];
    const int wv = threadIdx.x >> 6;
    if ((threadIdx.x & 63) == 0) redm[wv] = mx;
    __syncthreads();
    mx = fmaxf(fmaxf(redm[0], redm[1]), fmaxf(redm[2], redm[3]));
    float sum = 0.f;
#pragma unroll
    for (int j = 0; j < 8; ++j) { v[j] = expf(v[j] - mx); sum += v[j]; }
    for (int off = 32; off; off >>= 1) sum += __shfl_xor(sum, off, 64);
    if ((threadIdx.x & 63) == 0) reds[wv] = sum;
    __syncthreads();
    const float inv = 1.0f / (reds[0] + reds[1] + reds[2] + reds[3]);
    f16x8 o;
#pragma unroll
    for (int j = 0; j < 8; ++j) o[j] = (_Float16)(v[j] * inv);
    *(f16x8*)(P + (size_t)row * 2048 + threadIdx.x * 8) = o;
}

// ---------------------------------------------------------------------------
extern "C" void kernel_launch(void* const* d_in, const int* in_sizes, int n_in,
                              void* d_out, int out_size, void* d_ws, size_t ws_size,
                              hipStream_t stream)
{
    (void)in_sizes; (void)n_in; (void)out_size;
    const float* x  = (const float*)d_in[0];
    const float* Wq = (const float*)d_in[1];
    const float* bq = (const float*)d_in[2];
    const float* Wk = (const float*)d_in[3];
    const float* bk = (const float*)d_in[4];
    const float* Wv = (const float*)d_in[5];
    const float* bv = (const float*)d_in[6];
    const float* Wo = (const float*)d_in[7];
    const float* bo = (const float*)d_in[8];
    float* out = (float*)d_out;

    constexpr int S = 2048, D = 1024, H = 1024, NBATCH = 4;
    constexpr size_t M  = (size_t)NBATCH * S;   // 8192
    constexpr size_t SH = (size_t)S * H;        // per-batch q/k/v elems
    constexpr size_t SS = (size_t)S * S;        // per-batch score elems
    constexpr size_t QK = (size_t)S * 2048;     // per-batch fused qk row-block

    char* w = (char*)d_ws;
    size_t off = 0;
    auto alloc = [&](size_t bytes) -> char* {
        char* p = w + off;
        off += (bytes + 255) & ~(size_t)255;
        return p;
    };

    _Float16* xh   = (_Float16*)alloc(M * D * 2);
    _Float16* wqkT = (_Float16*)alloc((size_t)2 * D * H * 2);  // [2048][1024]
    _Float16* wvh  = (_Float16*)alloc((size_t)D * H * 2);
    _Float16* woh  = (_Float16*)alloc((size_t)H * D * 2);
    float*    bqk  = (float*)alloc(2048 * 4);
    _Float16* qkh  = (_Float16*)alloc(M * 2048 * 2);  // [8192][2048] q|k hi
    _Float16* qkl  = (_Float16*)alloc(M * 2048 * 2);  // residual (q cols only)
    _Float16* vT   = (_Float16*)alloc(M * H * 2);
    _Float16* yh   = xh;  // x dead after projections; reuse for y

    int NB = 1;
    if (ws_size >= off + (size_t)4 * SS * 4 + (size_t)4 * SS * 2 + 1024) NB = 4;
    float*    sc = (float*)alloc((size_t)NB * SS * 4);
    _Float16* Ph = (_Float16*)alloc((size_t)NB * SS * 2);

    // ---- convert / transpose / concat ----
    cvt_split_f16<<<dim3((unsigned)(M * D / 8 / 256)), 256, 0, stream>>>(
        x, xh, nullptr, (int)(M * D / 8));
    transpose4_f16<<<dim3(32, 32, 4), 256, 0, stream>>>(
        Wq, Wk, Wv, Wo, wqkT, wqkT + (size_t)D * H, wvh, woh);
    concat_bias<<<dim3(8), 256, 0, stream>>>(bq, bk, bqk);

    // ---- fused q|k projection (plain 256^2 pipelined): grid 8x32 = 256 wg --
    gemm_nt256<1><<<dim3(2048 / 256, M / 256), 512, 0, stream>>>(
        xh, wqkT, qkh, qkl, bqk,
        D, D, D, 2048, /*CaCols=*/1024, 0, 0, 0);

    // ---- v projection (transposed out), pipelined 128x256: grid 4x64 ----
    gemm_pl<2><<<dim3(H / 256, M / 128), 512, 0, stream>>>(
        xh, wvh, vT, bv, D, D, D, 0, 0, 0, 0);

    // ---- attention ----
    for (int b0 = 0; b0 < NBATCH; b0 += NB) {
        // scores = (qh+ql) * kh^T (split-A 256^2 pipelined)
        gemm_spa256<0><<<dim3(S / 256, S / 256, NB), 512, 0, stream>>>(
            qkh + (size_t)b0 * QK, qkl + (size_t)b0 * QK,
            qkh + (size_t)b0 * QK + 1024,
            sc, nullptr, nullptr,
            H, 2048, 2048, S, 0, QK, QK, SS);
        softmax_rows<<<dim3(NB * S), 256, 0, stream>>>(sc, Ph);
        // PV pipelined 128x256: grid 4x16x4 = 256 wg
        gemm_pl<1><<<dim3(H / 256, S / 128, NB), 512, 0, stream>>>(
            Ph, vT + (size_t)b0 * SH, yh + (size_t)b0 * SH, nullptr,
            S, S, S, H, SS, SH, SH);
    }

    // ---- output projection, pipelined 128x256: grid 4x64 ----
    gemm_pl<0><<<dim3(D / 256, M / 128), 512, 0, stream>>>(
        yh, woh, out, bo, H, H, H, D, 0, 0, 0);
}

// Round 16
// 234.788 us; speedup vs baseline: 1.0744x; 1.0116x over previous
//
#include <hip/hip_runtime.h>

typedef _Float16 f16x8 __attribute__((ext_vector_type(8)));
typedef float f32x4 __attribute__((ext_vector_type(4)));

#define GLD16(gp, lp) __builtin_amdgcn_global_load_lds(                     \
    (const __attribute__((address_space(1))) void*)(gp),                    \
    (__attribute__((address_space(3))) void*)(lp), 16, 0, 0)

// XCD-aware swizzle of the flattened 2D grid (requires nwg % 8 == 0).
__device__ inline void xcd_swizzle(int& bx, int& by) {
    const int nwg = gridDim.x * gridDim.y;
    const int flat = blockIdx.y * gridDim.x + blockIdx.x;
    const int cpx = nwg >> 3;
    const int swz = (flat & 7) * cpx + (flat >> 3);
    bx = swz % gridDim.x;
    by = swz / gridDim.x;
}

// ---------------------------------------------------------------------------
// Pipelined plain NT GEMM, 128x256 tile, BK=32, 8 waves (2M x 4N: 64x64/wave),
// TRIPLE-buffered LDS (72 KB), single barrier per K-tile.
// NT = K/32 (compile-time): guard-free main loop (NMAIN tiles) + static
// epilogue (REM = 2 or 4 tiles) — identical dynamic behavior to the rolled
// loop, bit-exact outputs.
// MODE 0: fp32 out (+bias).  MODE 1: fp16 out (+bias).
// MODE 2: fp16 out, per-batch transposed (v): out[(b*1024+col)*2048+s].
// ---------------------------------------------------------------------------
template <int MODE, int NT>
__global__ __launch_bounds__(512, 2)
void gemm_pl(const _Float16* __restrict__ A, const _Float16* __restrict__ B,
             void* __restrict__ C, const float* __restrict__ bias,
             int lda, int ldb, int ldc, size_t sA, size_t sB, size_t sC)
{
    constexpr int NMAIN = ((NT - 2) / 3) * 3;
    constexpr int REM   = NT - NMAIN;   // 2 (NT=32) or 4 (NT=64)
    __shared__ __align__(16) _Float16 lds[3][(128 + 256) * 32];   // 72 KB
    const int tid = threadIdx.x, wave = tid >> 6, lane = tid & 63;
    const int z = blockIdx.z;
    int bx, by; xcd_swizzle(bx, by);
    const int m0 = by * 128, n0 = bx * 256;

    const int trow = tid >> 2;
    const int schunk = (tid & 3) ^ ((trow >> 1) & 3);
    const char* pA = (const char*)(A + (size_t)z * sA + (size_t)(m0 + trow) * lda) + schunk * 16;
    const char* pB = (const char*)(B + (size_t)z * sB + (size_t)(n0 + trow) * ldb) + schunk * 16;
    const size_t hB = (size_t)128 * ldb * 2;

    auto stage = [&](int bf) {
        char* dA = (char*)&lds[bf][0] + tid * 16;
        char* dB = (char*)&lds[bf][128 * 32] + tid * 16;
        GLD16(pA, dA);
        GLD16(pB, dB); GLD16(pB + hB, dB + 8192);
        pA += 64; pB += 64;
    };

    const int wr = (wave >> 2) * 64, wcol = (wave & 3) * 64;
    const int fr = lane & 15;
    const int ckq = ((lane >> 4) ^ ((fr >> 1) & 3)) * 8;
    const int aoff = (wr + fr) * 32 + ckq;
    const int boff = (wcol + fr) * 32 + ckq;

    const f32x4 zero = {0.f, 0.f, 0.f, 0.f};
    f32x4 acc[4][4];
#pragma unroll
    for (int i = 0; i < 4; ++i)
#pragma unroll
        for (int j = 0; j < 4; ++j) acc[i][j] = zero;

    auto tile = [&](int buf, bool doStage, int stBuf, bool vm6) {
        if (doStage) stage(stBuf);
        const _Float16* bA = &lds[buf][0];
        const _Float16* bB = &lds[buf][128 * 32];
        f16x8 af[4], bf4[4];
#pragma unroll
        for (int i = 0; i < 4; ++i)
            af[i] = *(const f16x8*)(bA + aoff + i * 512);
#pragma unroll
        for (int j = 0; j < 4; ++j)
            bf4[j] = *(const f16x8*)(bB + boff + j * 512);
        __builtin_amdgcn_s_setprio(1);
#pragma unroll
        for (int i = 0; i < 4; ++i)
#pragma unroll
            for (int j = 0; j < 4; ++j)
                acc[i][j] = __builtin_amdgcn_mfma_f32_16x16x32_f16(af[i], bf4[j], acc[i][j], 0, 0, 0);
        __builtin_amdgcn_s_setprio(0);
        __builtin_amdgcn_sched_barrier(0);
        if (vm6) { asm volatile("s_waitcnt vmcnt(3)" ::: "memory"); }
        else     { asm volatile("s_waitcnt vmcnt(0)" ::: "memory"); }
        __builtin_amdgcn_s_barrier();
        __builtin_amdgcn_sched_barrier(0);
    };

    stage(0); stage(1);
    asm volatile("s_waitcnt vmcnt(3)" ::: "memory");
    __builtin_amdgcn_s_barrier();
    __builtin_amdgcn_sched_barrier(0);

    for (int tb = 0; tb < NMAIN; tb += 3) {   // guard-free main section
#pragma unroll
        for (int u = 0; u < 3; ++u)
            tile(u, true, (u + 2) % 3, true);
    }
#pragma unroll
    for (int e = 0; e < REM; ++e)             // static epilogue
        tile(e % 3, e < REM - 2, (e + 2) % 3, e < REM - 2);

    const int r0 = (lane >> 4) * 4;
#pragma unroll
    for (int j = 0; j < 4; ++j) {
        const int col = n0 + wcol + j * 16 + fr;
        const float bv = bias ? bias[col] : 0.0f;
#pragma unroll
        for (int i = 0; i < 4; ++i) {
            const int row = m0 + wr + i * 16 + r0;
            if constexpr (MODE == 0) {
                float* p = (float*)C + (size_t)z * sC + (size_t)row * ldc + col;
                p[0]               = acc[i][j][0] + bv;
                p[(size_t)ldc]     = acc[i][j][1] + bv;
                p[(size_t)2 * ldc] = acc[i][j][2] + bv;
                p[(size_t)3 * ldc] = acc[i][j][3] + bv;
            } else if constexpr (MODE == 1) {
                _Float16* p = (_Float16*)C + (size_t)z * sC + (size_t)row * ldc + col;
                p[0]               = (_Float16)(acc[i][j][0] + bv);
                p[(size_t)ldc]     = (_Float16)(acc[i][j][1] + bv);
                p[(size_t)2 * ldc] = (_Float16)(acc[i][j][2] + bv);
                p[(size_t)3 * ldc] = (_Float16)(acc[i][j][3] + bv);
            } else {
                const int bb = row >> 11, s = row & 2047;
                _Float16* p = (_Float16*)C + (((size_t)(bb << 10) + col) << 11) + s;
                p[0] = (_Float16)(acc[i][j][0] + bv);
                p[1] = (_Float16)(acc[i][j][1] + bv);
                p[2] = (_Float16)(acc[i][j][2] + bv);
                p[3] = (_Float16)(acc[i][j][3] + bv);
            }
        }
    }
}

// ---------------------------------------------------------------------------
// Split-A NT GEMM, 256x256 tile, BK=32, 8 waves (4M x 2N: 64x128/wave),
// TRIPLE-buffered LDS (144 KB), single barrier per K-tile; NT compile-time
// (guard-free main + static epilogue). C = Ah*B + Al*B, fp32 out. Bit-exact.
// ---------------------------------------------------------------------------
template <int NT>
__global__ __launch_bounds__(512, 2)
void gemm_spa256(const _Float16* __restrict__ Ah, const _Float16* __restrict__ Al,
                 const _Float16* __restrict__ B, float* __restrict__ Cm,
                 int lda, int ldb, int ldc,
                 size_t sA, size_t sB, size_t sC)
{
    constexpr int NMAIN = ((NT - 2) / 3) * 3;
    constexpr int REM   = NT - NMAIN;
    __shared__ __align__(16) _Float16 lds[3][3][256 * 32];   // 144 KB
    const int tid = threadIdx.x, wave = tid >> 6, lane = tid & 63;
    const int z = blockIdx.z;
    int bx, by; xcd_swizzle(bx, by);
    const int m0 = by * 256, n0 = bx * 256;

    const int trow = tid >> 2;
    const int schunk = (tid & 3) ^ ((trow >> 1) & 3);
    const char* pAh = (const char*)(Ah + (size_t)z * sA + (size_t)(m0 + trow) * lda) + schunk * 16;
    const char* pAl = (const char*)(Al + (size_t)z * sA + (size_t)(m0 + trow) * lda) + schunk * 16;
    const char* pB  = (const char*)(B  + (size_t)z * sB + (size_t)(n0 + trow) * ldb) + schunk * 16;
    const size_t hA = (size_t)128 * lda * 2;
    const size_t hB = (size_t)128 * ldb * 2;

    auto stage = [&](int bf) {
        char* d0 = (char*)&lds[bf][0][0] + tid * 16;
        char* d1 = (char*)&lds[bf][1][0] + tid * 16;
        char* d2 = (char*)&lds[bf][2][0] + tid * 16;
        GLD16(pAh, d0); GLD16(pAh + hA, d0 + 8192);
        GLD16(pAl, d1); GLD16(pAl + hA, d1 + 8192);
        GLD16(pB,  d2); GLD16(pB  + hB, d2 + 8192);
        pAh += 64; pAl += 64; pB += 64;
    };

    const int wr = (wave >> 1) * 64, wcol = (wave & 1) * 128;
    const int fr = lane & 15;
    const int ckq = ((lane >> 4) ^ ((fr >> 1) & 3)) * 8;
    const int aoff = (wr + fr) * 32 + ckq;
    const int boff = (wcol + fr) * 32 + ckq;

    const f32x4 zero = {0.f, 0.f, 0.f, 0.f};
    f32x4 acc[4][8];
#pragma unroll
    for (int i = 0; i < 4; ++i)
#pragma unroll
        for (int j = 0; j < 8; ++j) acc[i][j] = zero;

    auto tile = [&](int buf, bool doStage, int stBuf, bool vm6) {
        if (doStage) stage(stBuf);
        const _Float16* bAh = &lds[buf][0][0];
        const _Float16* bAl = &lds[buf][1][0];
        const _Float16* bB  = &lds[buf][2][0];
        f16x8 af[4], al4[4], bf8[8];
#pragma unroll
        for (int i = 0; i < 4; ++i) {
            af[i]  = *(const f16x8*)(bAh + aoff + i * 512);
            al4[i] = *(const f16x8*)(bAl + aoff + i * 512);
        }
#pragma unroll
        for (int j = 0; j < 8; ++j)
            bf8[j] = *(const f16x8*)(bB + boff + j * 512);
        __builtin_amdgcn_s_setprio(1);
#pragma unroll
        for (int i = 0; i < 4; ++i)
#pragma unroll
            for (int j = 0; j < 8; ++j) {
                acc[i][j] = __builtin_amdgcn_mfma_f32_16x16x32_f16(af[i],  bf8[j], acc[i][j], 0, 0, 0);
                acc[i][j] = __builtin_amdgcn_mfma_f32_16x16x32_f16(al4[i], bf8[j], acc[i][j], 0, 0, 0);
            }
        __builtin_amdgcn_s_setprio(0);
        __builtin_amdgcn_sched_barrier(0);
        if (vm6) { asm volatile("s_waitcnt vmcnt(6)" ::: "memory"); }
        else     { asm volatile("s_waitcnt vmcnt(0)" ::: "memory"); }
        __builtin_amdgcn_s_barrier();
        __builtin_amdgcn_sched_barrier(0);
    };

    stage(0); stage(1);
    asm volatile("s_waitcnt vmcnt(6)" ::: "memory");
    __builtin_amdgcn_s_barrier();
    __builtin_amdgcn_sched_barrier(0);

    for (int tb = 0; tb < NMAIN; tb += 3) {
#pragma unroll
        for (int u = 0; u < 3; ++u)
            tile(u, true, (u + 2) % 3, true);
    }
#pragma unroll
    for (int e = 0; e < REM; ++e)
        tile(e % 3, e < REM - 2, (e + 2) % 3, e < REM - 2);

    const int r0 = (lane >> 4) * 4;
#pragma unroll
    for (int j = 0; j < 8; ++j) {
        const int col = n0 + wcol + j * 16 + fr;
#pragma unroll
        for (int i = 0; i < 4; ++i) {
            const int row = m0 + wr + i * 16 + r0;
            float* p = Cm + (size_t)z * sC + (size_t)row * ldc + col;
            p[0]               = acc[i][j][0];
            p[(size_t)ldc]     = acc[i][j][1];
            p[(size_t)2 * ldc] = acc[i][j][2];
            p[(size_t)3 * ldc] = acc[i][j][3];
        }
    }
}

// ---------------------------------------------------------------------------
// Plain NT GEMM, 256x256 tile, BK=32, 8 waves (4M x 2N), TRIPLE-buffered
// (96 KB), single barrier per K-tile; NT compile-time. fp16 hi out (+bias)
// + residual Ca for col < CaCols.  Bit-exact chains.
// ---------------------------------------------------------------------------
template <int NT>
__global__ __launch_bounds__(512, 2)
void gemm_nt256(const _Float16* __restrict__ A, const _Float16* __restrict__ B,
                _Float16* __restrict__ Cm, _Float16* __restrict__ Ca,
                const float* __restrict__ bias,
                int lda, int ldb, int ldc, int CaCols,
                size_t sA, size_t sB, size_t sC)
{
    constexpr int NMAIN = ((NT - 2) / 3) * 3;
    constexpr int REM   = NT - NMAIN;
    __shared__ __align__(16) _Float16 lds[3][2][256 * 32];   // 96 KB
    const int tid = threadIdx.x, wave = tid >> 6, lane = tid & 63;
    const int z = blockIdx.z;
    int bx, by; xcd_swizzle(bx, by);
    const int m0 = by * 256, n0 = bx * 256;

    const int trow = tid >> 2;
    const int schunk = (tid & 3) ^ ((trow >> 1) & 3);
    const char* pA = (const char*)(A + (size_t)z * sA + (size_t)(m0 + trow) * lda) + schunk * 16;
    const char* pB = (const char*)(B + (size_t)z * sB + (size_t)(n0 + trow) * ldb) + schunk * 16;
    const size_t hA = (size_t)128 * lda * 2;
    const size_t hB = (size_t)128 * ldb * 2;

    auto stage = [&](int bf) {
        char* d0 = (char*)&lds[bf][0][0] + tid * 16;
        char* d1 = (char*)&lds[bf][1][0] + tid * 16;
        GLD16(pA, d0); GLD16(pA + hA, d0 + 8192);
        GLD16(pB, d1); GLD16(pB + hB, d1 + 8192);
        pA += 64; pB += 64;
    };

    const int wr = (wave >> 1) * 64, wcol = (wave & 1) * 128;
    const int fr = lane & 15;
    const int ckq = ((lane >> 4) ^ ((fr >> 1) & 3)) * 8;
    const int aoff = (wr + fr) * 32 + ckq;
    const int boff = (wcol + fr) * 32 + ckq;

    const f32x4 zero = {0.f, 0.f, 0.f, 0.f};
    f32x4 acc[4][8];
#pragma unroll
    for (int i = 0; i < 4; ++i)
#pragma unroll
        for (int j = 0; j < 8; ++j) acc[i][j] = zero;

    auto tile = [&](int buf, bool doStage, int stBuf, bool vm6) {
        if (doStage) stage(stBuf);
        const _Float16* bA = &lds[buf][0][0];
        const _Float16* bB = &lds[buf][1][0];
        f16x8 af[4], bf8[8];
#pragma unroll
        for (int i = 0; i < 4; ++i)
            af[i] = *(const f16x8*)(bA + aoff + i * 512);
#pragma unroll
        for (int j = 0; j < 8; ++j)
            bf8[j] = *(const f16x8*)(bB + boff + j * 512);
        __builtin_amdgcn_s_setprio(1);
#pragma unroll
        for (int i = 0; i < 4; ++i)
#pragma unroll
            for (int j = 0; j < 8; ++j)
                acc[i][j] = __builtin_amdgcn_mfma_f32_16x16x32_f16(af[i], bf8[j], acc[i][j], 0, 0, 0);
        __builtin_amdgcn_s_setprio(0);
        __builtin_amdgcn_sched_barrier(0);
        if (vm6) { asm volatile("s_waitcnt vmcnt(4)" ::: "memory"); }
        else     { asm volatile("s_waitcnt vmcnt(0)" ::: "memory"); }
        __builtin_amdgcn_s_barrier();
        __builtin_amdgcn_sched_barrier(0);
    };

    stage(0); stage(1);
    asm volatile("s_waitcnt vmcnt(4)" ::: "memory");
    __builtin_amdgcn_s_barrier();
    __builtin_amdgcn_sched_barrier(0);

    for (int tb = 0; tb < NMAIN; tb += 3) {
#pragma unroll
        for (int u = 0; u < 3; ++u)
            tile(u, true, (u + 2) % 3, true);
    }
#pragma unroll
    for (int e = 0; e < REM; ++e)
        tile(e % 3, e < REM - 2, (e + 2) % 3, e < REM - 2);

    const int r0 = (lane >> 4) * 4;
#pragma unroll
    for (int j = 0; j < 8; ++j) {
        const int col = n0 + wcol + j * 16 + fr;
        const float bv = bias ? bias[col] : 0.0f;
#pragma unroll
        for (int i = 0; i < 4; ++i) {
            const int row = m0 + wr + i * 16 + r0;
#pragma unroll
            for (int r = 0; r < 4; ++r) {
                const float val = acc[i][j][r] + bv;
                const size_t idx = (size_t)z * sC + (size_t)(row + r) * ldc + col;
                const _Float16 hv = (_Float16)val;
                Cm[idx] = hv;
                if (col < CaCols) Ca[idx] = (_Float16)(val - (float)hv);
            }
        }
    }
}

// ---------------------------------------------------------------------------
// fp32 -> fp16 (hi only; residual path unused since round 7).
// ---------------------------------------------------------------------------
__global__ __launch_bounds__(256)
void cvt_split_f16(const float* __restrict__ in, _Float16* __restrict__ hi,
                   _Float16* __restrict__ lo, int n8)
{
    const int t = blockIdx.x * 256 + threadIdx.x;
    if (t >= n8) return;
    const float4* p = (const float4*)in + (size_t)t * 2;
    const float4 a = p[0], b = p[1];
    const float v[8] = {a.x, a.y, a.z, a.w, b.x, b.y, b.z, b.w};
    f16x8 h, l;
#pragma unroll
    for (int j = 0; j < 8; ++j) {
        const _Float16 hv = (_Float16)v[j];
        h[j] = hv;
        l[j] = (_Float16)(v[j] - (float)hv);
    }
    ((f16x8*)hi)[t] = h;
    if (lo) ((f16x8*)lo)[t] = l;
}

// ---------------------------------------------------------------------------
// Batched 1024x1024 fp32 -> fp16 transpose of the 4 weight matrices (z=0..3).
// ---------------------------------------------------------------------------
__global__ __launch_bounds__(256)
void transpose4_f16(const float* __restrict__ W0, const float* __restrict__ W1,
                    const float* __restrict__ W2, const float* __restrict__ W3,
                    _Float16* __restrict__ T0, _Float16* __restrict__ T1,
                    _Float16* __restrict__ T2, _Float16* __restrict__ T3)
{
    constexpr int N = 1024;
    const int zi = blockIdx.z;
    const float* W = (zi == 0) ? W0 : (zi == 1) ? W1 : (zi == 2) ? W2 : W3;
    _Float16*   T = (zi == 0) ? T0 : (zi == 1) ? T1 : (zi == 2) ? T2 : T3;
    __shared__ float t[32][33];
    const int c0 = blockIdx.x * 32, r0 = blockIdx.y * 32;
    const int tx = threadIdx.x & 31, ty = threadIdx.x >> 5;
#pragma unroll
    for (int r = ty; r < 32; r += 8)
        t[r][tx] = W[(size_t)(r0 + r) * N + (c0 + tx)];
    __syncthreads();
#pragma unroll
    for (int r = ty; r < 32; r += 8)
        T[(size_t)(c0 + r) * N + (r0 + tx)] = (_Float16)t[tx][r];
}

// ---------------------------------------------------------------------------
// Concatenate two 1024-float bias vectors.
// ---------------------------------------------------------------------------
__global__ __launch_bounds__(256)
void concat_bias(const float* __restrict__ a, const float* __restrict__ b,
                 float* __restrict__ o)
{
    const int t = blockIdx.x * 256 + threadIdx.x;
    o[t] = (t < 1024) ? a[t] : b[t - 1024];
}

// ---------------------------------------------------------------------------
// Row softmax: fp32 scores [rows, 2048] -> fp16 probs. One block per row.
// ---------------------------------------------------------------------------
__global__ __launch_bounds__(256)
void softmax_rows(const float* __restrict__ S, _Float16* __restrict__ P)
{
    const int row = blockIdx.x;
    const float* s = S + (size_t)row * 2048 + threadIdx.x * 8;
    float v[8];
    const float4 a = *(const float4*)s;
    const float4 b = *(const float4*)(s + 4);
    v[0] = a.x; v[1] = a.y; v[2] = a.z; v[3] = a.w;
    v[4] = b.x; v[5] = b.y; v[6] = b.z; v[7] = b.w;
    float mx = v[0];
#pragma unroll
    for (int j = 1; j < 8; ++j) mx = fmaxf(mx, v[j]);
    for (int off = 32; off; off >>= 1) mx = fmaxf(mx, __shfl_xor(mx, off, 64));
    __shared__ float redm[4], reds[4];
    const int wv = threadIdx.x >> 6;
    if ((threadIdx.x & 63) == 0) redm[wv] = mx;
    __syncthreads();
    mx = fmaxf(fmaxf(redm[0], redm[1]), fmaxf(redm[2], redm[3]));
    float sum = 0.f;
#pragma unroll
    for (int j = 0; j < 8; ++j) { v[j] = expf(v[j] - mx); sum += v[j]; }
    for (int off = 32; off; off >>= 1) sum += __shfl_xor(sum, off, 64);
    if ((threadIdx.x & 63) == 0) reds[wv] = sum;
    __syncthreads();
    const float inv = 1.0f / (reds[0] + reds[1] + reds[2] + reds[3]);
    f16x8 o;
#pragma unroll
    for (int j = 0; j < 8; ++j) o[j] = (_Float16)(v[j] * inv);
    *(f16x8*)(P + (size_t)row * 2048 + threadIdx.x * 8) = o;
}

// ---------------------------------------------------------------------------
extern "C" void kernel_launch(void* const* d_in, const int* in_sizes, int n_in,
                              void* d_out, int out_size, void* d_ws, size_t ws_size,
                              hipStream_t stream)
{
    (void)in_sizes; (void)n_in; (void)out_size;
    const float* x  = (const float*)d_in[0];
    const float* Wq = (const float*)d_in[1];
    const float* bq = (const float*)d_in[2];
    const float* Wk = (const float*)d_in[3];
    const float* bk = (const float*)d_in[4];
    const float* Wv = (const float*)d_in[5];
    const float* bv = (const float*)d_in[6];
    const float* Wo = (const float*)d_in[7];
    const float* bo = (const float*)d_in[8];
    float* out = (float*)d_out;

    constexpr int S = 2048, D = 1024, H = 1024, NBATCH = 4;
    constexpr size_t M  = (size_t)NBATCH * S;   // 8192
    constexpr size_t SH = (size_t)S * H;        // per-batch q/k/v elems
    constexpr size_t SS = (size_t)S * S;        // per-batch score elems
    constexpr size_t QK = (size_t)S * 2048;     // per-batch fused qk row-block

    char* w = (char*)d_ws;
    size_t off = 0;
    auto alloc = [&](size_t bytes) -> char* {
        char* p = w + off;
        off += (bytes + 255) & ~(size_t)255;
        return p;
    };

    _Float16* xh   = (_Float16*)alloc(M * D * 2);
    _Float16* wqkT = (_Float16*)alloc((size_t)2 * D * H * 2);  // [2048][1024]
    _Float16* wvh  = (_Float16*)alloc((size_t)D * H * 2);
    _Float16* woh  = (_Float16*)alloc((size_t)H * D * 2);
    float*    bqk  = (float*)alloc(2048 * 4);
    _Float16* qkh  = (_Float16*)alloc(M * 2048 * 2);  // [8192][2048] q|k hi
    _Float16* qkl  = (_Float16*)alloc(M * 2048 * 2);  // residual (q cols only)
    _Float16* vT   = (_Float16*)alloc(M * H * 2);
    _Float16* yh   = xh;  // x dead after projections; reuse for y

    int NB = 1;
    if (ws_size >= off + (size_t)4 * SS * 4 + (size_t)4 * SS * 2 + 1024) NB = 4;
    float*    sc = (float*)alloc((size_t)NB * SS * 4);
    _Float16* Ph = (_Float16*)alloc((size_t)NB * SS * 2);

    // ---- convert / transpose / concat ----
    cvt_split_f16<<<dim3((unsigned)(M * D / 8 / 256)), 256, 0, stream>>>(
        x, xh, nullptr, (int)(M * D / 8));
    transpose4_f16<<<dim3(32, 32, 4), 256, 0, stream>>>(
        Wq, Wk, Wv, Wo, wqkT, wqkT + (size_t)D * H, wvh, woh);
    concat_bias<<<dim3(8), 256, 0, stream>>>(bq, bk, bqk);

    // ---- fused q|k projection (plain 256^2 pipelined): grid 8x32 = 256 wg --
    gemm_nt256<32><<<dim3(2048 / 256, M / 256), 512, 0, stream>>>(
        xh, wqkT, qkh, qkl, bqk,
        D, D, 2048, /*CaCols=*/1024, 0, 0, 0);

    // ---- v projection (transposed out), pipelined 128x256: grid 4x64 ----
    gemm_pl<2, 32><<<dim3(H / 256, M / 128), 512, 0, stream>>>(
        xh, wvh, vT, bv, D, D, 0, 0, 0, 0);

    // ---- attention ----
    for (int b0 = 0; b0 < NBATCH; b0 += NB) {
        // scores = (qh+ql) * kh^T (split-A 256^2 pipelined)
        gemm_spa256<32><<<dim3(S / 256, S / 256, NB), 512, 0, stream>>>(
            qkh + (size_t)b0 * QK, qkl + (size_t)b0 * QK,
            qkh + (size_t)b0 * QK + 1024,
            sc, 2048, 2048, S, QK, QK, SS);
        softmax_rows<<<dim3(NB * S), 256, 0, stream>>>(sc, Ph);
        // PV pipelined 128x256 (K=2048 -> NT=64): grid 4x16x4 = 256 wg
        gemm_pl<1, 64><<<dim3(H / 256, S / 128, NB), 512, 0, stream>>>(
            Ph, vT + (size_t)b0 * SH, yh + (size_t)b0 * SH, nullptr,
            S, S, H, SS, SH, SH);
    }

    // ---- output projection, pipelined 128x256: grid 4x64 ----
    gemm_pl<0, 32><<<dim3(D / 256, M / 128), 512, 0, stream>>>(
        yh, woh, out, bo, H, H, D, 0, 0, 0);
}